// Round 11
// baseline (156.416 us; speedup 1.0000x reference)
//
#include <hip/hip_runtime.h>

#define BC 16
#define NN 2048
#define FF 128
#define DD 128
#define NEDGES 65536
#define NEG_INF -1e16f
#define LEAK 0.1f
#define CAPR 128   // per-row in-degree cap; P(Poisson(32) > 128) ~ 1e-35

// ---------------- Kernel 1 (fused): edge atomicOr + z = h @ W ------------
// blocks 0..255: set adjacency bits (mask pre-zeroed by hipMemsetAsync).
// blocks 256..1279: register-tiled zgemm, one [32 x 128] tile of z each.
__global__ void __launch_bounds__(256) zedge_kernel(const float* __restrict__ h,
                                                    const float* __restrict__ W,
                                                    float* __restrict__ z,
                                                    const int* __restrict__ row,
                                                    const int* __restrict__ col,
                                                    unsigned int* __restrict__ mask) {
    const int tid = threadIdx.x;
    const int blk = blockIdx.x;

    if (blk < 256) {   // ---- edge part
        const int e = blk * 256 + tid;
        const unsigned int key = (unsigned int)row[e] * NN + (unsigned int)col[e];
        atomicOr(&mask[key >> 5], 1u << (key & 31u));
        return;
    }

    // ---- zgemm part
    __shared__ float hs[32][FF];   // 16 KB
    const size_t row0 = (size_t)(blk - 256) * 32;
    const float4* hv = (const float4*)(h + row0 * FF);
    float4* hsv = (float4*)&hs[0][0];
#pragma unroll
    for (int i = 0; i < 4; ++i) hsv[tid + 256 * i] = hv[tid + 256 * i];
    __syncthreads();

    const int c0 = (tid & 31) * 4;
    const int r0 = (tid >> 5) * 4;
    float acc[4][4] = {};
    for (int f = 0; f < FF; f += 4) {
        float4 a[4], bb[4];
#pragma unroll
        for (int r = 0; r < 4; ++r) a[r] = *(const float4*)&hs[r0 + r][f];
#pragma unroll
        for (int k = 0; k < 4; ++k) bb[k] = *(const float4*)&W[(f + k) * DD + c0];
#pragma unroll
        for (int r = 0; r < 4; ++r) {
            acc[r][0] += a[r].x * bb[0].x + a[r].y * bb[1].x + a[r].z * bb[2].x + a[r].w * bb[3].x;
            acc[r][1] += a[r].x * bb[0].y + a[r].y * bb[1].y + a[r].z * bb[2].y + a[r].w * bb[3].y;
            acc[r][2] += a[r].x * bb[0].z + a[r].y * bb[1].z + a[r].z * bb[2].z + a[r].w * bb[3].z;
            acc[r][3] += a[r].x * bb[0].w + a[r].y * bb[1].w + a[r].z * bb[2].w + a[r].w * bb[3].w;
        }
    }
#pragma unroll
    for (int r = 0; r < 4; ++r)
        *(float4*)&z[(row0 + r0 + r) * DD + c0] =
            make_float4(acc[r][0], acc[r][1], acc[r][2], acc[r][3]);
}

// ---------------- Kernel 2: bitmask -> sorted CSR + 8-pad, zero atomics --
// one wave per row; shuffle prefix-scan of popcounts assigns slots. The lane
// holding the LAST edge also replicates its col into slots deg..pad8(deg)-1
// so gat can index hrow[e] unconditionally (no min/cndmask in the hot loop).
__global__ void __launch_bounds__(256) csr_kernel(const unsigned int* __restrict__ mask,
                                                  unsigned short* __restrict__ hits_g,
                                                  int* __restrict__ deg) {
    const int tid = threadIdx.x, wv = tid >> 6, ln = tid & 63;
    const int n = blockIdx.x * 4 + wv;
    unsigned int bits = mask[n * 64 + ln];
    const int cnt = __popc(bits);
    int pre = cnt;
#pragma unroll
    for (int off = 1; off <= 32; off <<= 1) {
        const int t = __shfl_up(pre, off, 64);
        if (ln >= off) pre += t;
    }
    const int tot = __shfl(pre, 63, 64);   // row degree, all lanes
    if (ln == 63) deg[n] = tot;
    int slot = pre - cnt;
    int lc = 0;
    while (bits) {
        const int bit = __ffs(bits) - 1;
        bits &= bits - 1;
        lc = ln * 32 + bit;
        if (slot < CAPR) hits_g[n * CAPR + slot] = (unsigned short)lc;
        ++slot;
    }
    // pad: unique lane with cnt>0 whose inclusive prefix == tot owns the last edge
    if (cnt > 0 && pre == tot && tot < CAPR) {
        const int padded = (tot + 7) & ~7;
        for (int j = tot; j < padded && j < CAPR; ++j)
            hits_g[n * CAPR + j] = (unsigned short)lc;
    }
}

// ---------------- Kernel 3: online softmax, score-stage pipelined --------
// One wave per (b,n) row, 4 independent waves/block, no LDS/barriers.
// b-swizzle pins 2 batches of z per XCD L2. Lane = (eq 0..7, hq 0..7).
// R10 showed gat is chain-bound, not VALU-bound (packing cut VALUBusy, not
// time). The chain was: gather -> dot -> 3 shuffles -> online update. Here
// chunk c+1's FULL score (gather+dot+shuffles+leaky) is computed before
// chunk c's (m,l,acc) update is applied, so shuffle latency overlaps the
// acc FMAs. Carried chain/chunk: fmax + 2 exp + fma only.
__global__ void __launch_bounds__(256) gat_kernel(const float* __restrict__ z,
                                                  const unsigned short* __restrict__ hits_g,
                                                  const int* __restrict__ deg,
                                                  float* __restrict__ out) {
    const int tid = threadIdx.x, wv = tid >> 6, ln = tid & 63;
    const int blk = blockIdx.x;
    const int b = ((blk & 7) << 1) | (wv & 1);
    const int n = ((blk >> 3) << 1) | (wv >> 1);
    const int eq = ln >> 3, hq = ln & 7;

    const float* zb = z + ((size_t)b << 18);   // b*2048*128
    const int nh = min(deg[n], CAPR);
    const unsigned short* hrow = hits_g + n * CAPR;

    const float4* znp = (const float4*)(zb + ((size_t)n << 7) + (hq << 4));
    const float4 a0 = znp[0], a1 = znp[1], a2 = znp[2], a3 = znp[3];

    float m = NEG_INF, l = 0.f;
    float4 acc0 = make_float4(0.f, 0.f, 0.f, 0.f), acc1 = acc0, acc2 = acc0, acc3 = acc0;

    if (nh > 0) {
        // ---- stage chunk 0: gather + full score (list is 8-padded)
        int he = hrow[eq];
        const float4* zc = (const float4*)(zb + ((size_t)he << 7) + (hq << 4));
        float4 v0 = zc[0], v1 = zc[1], v2 = zc[2], v3 = zc[3];
        float pt = a0.x * v0.x + a0.y * v0.y + a0.z * v0.z + a0.w * v0.w
                 + a1.x * v1.x + a1.y * v1.y + a1.z * v1.z + a1.w * v1.w
                 + a2.x * v2.x + a2.y * v2.y + a2.z * v2.z + a2.w * v2.w
                 + a3.x * v3.x + a3.y * v3.y + a3.z * v3.z + a3.w * v3.w;
        pt += __shfl_xor(pt, 1, 64);
        pt += __shfl_xor(pt, 2, 64);
        pt += __shfl_xor(pt, 4, 64);
        float sv = pt > 0.f ? pt : LEAK * pt;
        if (sv == 0.f || eq >= nh) sv = NEG_INF;

#pragma unroll 2
        for (int c0 = 0; c0 < nh; c0 += 8) {
            // keep current chunk's payload for the update below
            const float4 u0 = v0, u1 = v1, u2 = v2, u3 = v3;
            const float svc = sv;

            // ---- stage chunk c0+8 (independent of m/l/acc)
            const int nx = c0 + 8;
            if (nx < nh) {
                he = hrow[nx + eq];
                const float4* zn2 = (const float4*)(zb + ((size_t)he << 7) + (hq << 4));
                v0 = zn2[0]; v1 = zn2[1]; v2 = zn2[2]; v3 = zn2[3];
                float p2 = a0.x * v0.x + a0.y * v0.y + a0.z * v0.z + a0.w * v0.w
                         + a1.x * v1.x + a1.y * v1.y + a1.z * v1.z + a1.w * v1.w
                         + a2.x * v2.x + a2.y * v2.y + a2.z * v2.z + a2.w * v2.w
                         + a3.x * v3.x + a3.y * v3.y + a3.z * v3.z + a3.w * v3.w;
                p2 += __shfl_xor(p2, 1, 64);
                p2 += __shfl_xor(p2, 2, 64);
                p2 += __shfl_xor(p2, 4, 64);
                float s2 = p2 > 0.f ? p2 : LEAK * p2;    // leaky_relu(0.1)
                if (s2 == 0.f || nx + eq >= nh) s2 = NEG_INF;
                sv = s2;
            }

            // ---- apply chunk c0's online update (short carried chain)
            const float mnew = fmaxf(m, svc);
            const float alpha = __expf(m - mnew);        // 1 while m==mnew==NEG_INF
            const float pr = __expf(svc - mnew);
            l = l * alpha + pr;
            acc0.x = acc0.x * alpha + pr * u0.x; acc0.y = acc0.y * alpha + pr * u0.y;
            acc0.z = acc0.z * alpha + pr * u0.z; acc0.w = acc0.w * alpha + pr * u0.w;
            acc1.x = acc1.x * alpha + pr * u1.x; acc1.y = acc1.y * alpha + pr * u1.y;
            acc1.z = acc1.z * alpha + pr * u1.z; acc1.w = acc1.w * alpha + pr * u1.w;
            acc2.x = acc2.x * alpha + pr * u2.x; acc2.y = acc2.y * alpha + pr * u2.y;
            acc2.z = acc2.z * alpha + pr * u2.z; acc2.w = acc2.w * alpha + pr * u2.w;
            acc3.x = acc3.x * alpha + pr * u3.x; acc3.y = acc3.y * alpha + pr * u3.y;
            acc3.z = acc3.z * alpha + pr * u3.z; acc3.w = acc3.w * alpha + pr * u3.w;
            m = mnew;
        }
    }

    // ---- cross-eq merge: global row max, rescale, sum ----
    float M = m;
#pragma unroll
    for (int off = 8; off <= 32; off <<= 1) M = fmaxf(M, __shfl_xor(M, off, 64));

    if (nh > 0 && M > 0.5f * NEG_INF) {
        const float al = __expf(m - M);          // 0 for all-pad lanes
        l *= al;
        acc0.x *= al; acc0.y *= al; acc0.z *= al; acc0.w *= al;
        acc1.x *= al; acc1.y *= al; acc1.z *= al; acc1.w *= al;
        acc2.x *= al; acc2.y *= al; acc2.z *= al; acc2.w *= al;
        acc3.x *= al; acc3.y *= al; acc3.z *= al; acc3.w *= al;
#pragma unroll
        for (int off = 8; off <= 32; off <<= 1) {
            l += __shfl_xor(l, off, 64);
            acc0.x += __shfl_xor(acc0.x, off, 64); acc0.y += __shfl_xor(acc0.y, off, 64);
            acc0.z += __shfl_xor(acc0.z, off, 64); acc0.w += __shfl_xor(acc0.w, off, 64);
            acc1.x += __shfl_xor(acc1.x, off, 64); acc1.y += __shfl_xor(acc1.y, off, 64);
            acc1.z += __shfl_xor(acc1.z, off, 64); acc1.w += __shfl_xor(acc1.w, off, 64);
            acc2.x += __shfl_xor(acc2.x, off, 64); acc2.y += __shfl_xor(acc2.y, off, 64);
            acc2.z += __shfl_xor(acc2.z, off, 64); acc2.w += __shfl_xor(acc2.w, off, 64);
            acc3.x += __shfl_xor(acc3.x, off, 64); acc3.y += __shfl_xor(acc3.y, off, 64);
            acc3.z += __shfl_xor(acc3.z, off, 64); acc3.w += __shfl_xor(acc3.w, off, 64);
        }
        const float inv = 1.f / l;
        acc0.x *= inv; acc0.y *= inv; acc0.z *= inv; acc0.w *= inv;
        acc1.x *= inv; acc1.y *= inv; acc1.z *= inv; acc1.w *= inv;
        acc2.x *= inv; acc2.y *= inv; acc2.z *= inv; acc2.w *= inv;
        acc3.x *= inv; acc3.y *= inv; acc3.z *= inv; acc3.w *= inv;
    } else {
        // no valid edge: softmax over uniform -1e16 row -> mean of z[b]
        acc0 = make_float4(0.f, 0.f, 0.f, 0.f); acc1 = acc0; acc2 = acc0; acc3 = acc0;
        for (int mm = 0; mm < NN; ++mm) {
            const float4* zr = (const float4*)(zb + ((size_t)mm << 7) + (hq << 4));
            const float4 t0 = zr[0], t1 = zr[1], t2 = zr[2], t3 = zr[3];
            acc0.x += t0.x; acc0.y += t0.y; acc0.z += t0.z; acc0.w += t0.w;
            acc1.x += t1.x; acc1.y += t1.y; acc1.z += t1.z; acc1.w += t1.w;
            acc2.x += t2.x; acc2.y += t2.y; acc2.z += t2.z; acc2.w += t2.w;
            acc3.x += t3.x; acc3.y += t3.y; acc3.z += t3.z; acc3.w += t3.w;
        }
        const float s = 1.f / NN;
        acc0.x *= s; acc0.y *= s; acc0.z *= s; acc0.w *= s;
        acc1.x *= s; acc1.y *= s; acc1.z *= s; acc1.w *= s;
        acc2.x *= s; acc2.y *= s; acc2.z *= s; acc2.w *= s;
        acc3.x *= s; acc3.y *= s; acc3.z *= s; acc3.w *= s;
    }

    // store: lanes with eq<4 write float4 #eq of their hq slice (512 B/row)
    if (eq < 4) {
        float4 o = acc0;
        if (eq == 1) o = acc1;
        if (eq == 2) o = acc2;
        if (eq == 3) o = acc3;
        *(float4*)(out + (((size_t)b * NN + n) << 7) + (hq << 4) + (eq << 2)) = o;
    }
}

// ---------------- launcher ----------------
extern "C" void kernel_launch(void* const* d_in, const int* in_sizes, int n_in,
                              void* d_out, int out_size, void* d_ws, size_t ws_size,
                              hipStream_t stream) {
    const float* h = (const float*)d_in[0];
    const float* W = (const float*)d_in[1];
    const int* row = (const int*)d_in[2];
    const int* col = (const int*)d_in[3];
    float* out = (float*)d_out;

    char* ws = (char*)d_ws;
    float* z = (float*)ws;                                                     // 16 MB
    unsigned int* mask = (unsigned int*)(ws + (size_t)16 * 1024 * 1024);       // 512 KB
    unsigned short* hits_g = (unsigned short*)(ws + (size_t)16 * 1024 * 1024 + 512 * 1024); // 512 KB
    int* deg = (int*)(ws + (size_t)17 * 1024 * 1024);                          // 8 KB

    hipMemsetAsync(mask, 0, (size_t)NN * NN / 8, stream);   // DMA, ~2 us
    zedge_kernel<<<1280, 256, 0, stream>>>(h, W, z, row, col, mask);
    csr_kernel<<<NN / 4, 256, 0, stream>>>(mask, hits_g, deg);
    gat_kernel<<<(BC * NN) / 4, 256, 0, stream>>>(z, hits_g, deg, out);
}

// Round 12
// 152.698 us; speedup vs baseline: 1.0243x; 1.0243x over previous
//
#include <hip/hip_runtime.h>

#define BC 16
#define NN 2048
#define FF 128
#define DD 128
#define NEDGES 65536
#define NEG_INF -1e16f
#define LEAK 0.1f
#define CAPR 128        // per-row in-degree cap; P(Poisson(32) > 128) ~ 1e-35
#define LOG2E 1.44269504088896f

// ---------------- Kernel 1 (fused): edge atomicOr + z = h @ W ------------
// blocks 0..255: set adjacency bits (mask pre-zeroed by hipMemsetAsync).
// blocks 256..1279: register-tiled zgemm, one [32 x 128] tile of z each.
__global__ void __launch_bounds__(256) zedge_kernel(const float* __restrict__ h,
                                                    const float* __restrict__ W,
                                                    float* __restrict__ z,
                                                    const int* __restrict__ row,
                                                    const int* __restrict__ col,
                                                    unsigned int* __restrict__ mask) {
    const int tid = threadIdx.x;
    const int blk = blockIdx.x;

    if (blk < 256) {   // ---- edge part
        const int e = blk * 256 + tid;
        const unsigned int key = (unsigned int)row[e] * NN + (unsigned int)col[e];
        atomicOr(&mask[key >> 5], 1u << (key & 31u));
        return;
    }

    // ---- zgemm part
    __shared__ float hs[32][FF];   // 16 KB
    const size_t row0 = (size_t)(blk - 256) * 32;
    const float4* hv = (const float4*)(h + row0 * FF);
    float4* hsv = (float4*)&hs[0][0];
#pragma unroll
    for (int i = 0; i < 4; ++i) hsv[tid + 256 * i] = hv[tid + 256 * i];
    __syncthreads();

    const int c0 = (tid & 31) * 4;
    const int r0 = (tid >> 5) * 4;
    float acc[4][4] = {};
    for (int f = 0; f < FF; f += 4) {
        float4 a[4], bb[4];
#pragma unroll
        for (int r = 0; r < 4; ++r) a[r] = *(const float4*)&hs[r0 + r][f];
#pragma unroll
        for (int k = 0; k < 4; ++k) bb[k] = *(const float4*)&W[(f + k) * DD + c0];
#pragma unroll
        for (int r = 0; r < 4; ++r) {
            acc[r][0] += a[r].x * bb[0].x + a[r].y * bb[1].x + a[r].z * bb[2].x + a[r].w * bb[3].x;
            acc[r][1] += a[r].x * bb[0].y + a[r].y * bb[1].y + a[r].z * bb[2].y + a[r].w * bb[3].y;
            acc[r][2] += a[r].x * bb[0].z + a[r].y * bb[1].z + a[r].z * bb[2].z + a[r].w * bb[3].z;
            acc[r][3] += a[r].x * bb[0].w + a[r].y * bb[1].w + a[r].z * bb[2].w + a[r].w * bb[3].w;
        }
    }
#pragma unroll
    for (int r = 0; r < 4; ++r)
        *(float4*)&z[(row0 + r0 + r) * DD + c0] =
            make_float4(acc[r][0], acc[r][1], acc[r][2], acc[r][3]);
}

// ---------------- Kernel 2: bitmask -> sorted CSR + 8-pad, zero atomics --
// one wave per row; shuffle prefix-scan of popcounts assigns slots. The lane
// holding the LAST edge replicates its col into slots deg..pad8(deg)-1 so
// gat can index hrow[e] unconditionally (pads are score-masked via e>=nh).
__global__ void __launch_bounds__(256) csr_kernel(const unsigned int* __restrict__ mask,
                                                  unsigned short* __restrict__ hits_g,
                                                  int* __restrict__ deg) {
    const int tid = threadIdx.x, wv = tid >> 6, ln = tid & 63;
    const int n = blockIdx.x * 4 + wv;
    unsigned int bits = mask[n * 64 + ln];
    const int cnt = __popc(bits);
    int pre = cnt;
#pragma unroll
    for (int off = 1; off <= 32; off <<= 1) {
        const int t = __shfl_up(pre, off, 64);
        if (ln >= off) pre += t;
    }
    const int tot = __shfl(pre, 63, 64);   // row degree, all lanes
    if (ln == 63) deg[n] = tot;
    int slot = pre - cnt;
    int lc = 0;
    while (bits) {
        const int bit = __ffs(bits) - 1;
        bits &= bits - 1;
        lc = ln * 32 + bit;
        if (slot < CAPR) hits_g[n * CAPR + slot] = (unsigned short)lc;
        ++slot;
    }
    // pad: unique lane with cnt>0 whose inclusive prefix == tot owns the last edge
    if (cnt > 0 && pre == tot && tot < CAPR) {
        const int padded = (tot + 7) & ~7;
        for (int j = tot; j < padded && j < CAPR; ++j)
            hits_g[n * CAPR + j] = (unsigned short)lc;
    }
}

// ---------------- Kernel 3: single-pass, lane-local online softmax -------
// EXACT R9 structure (champion: 57.0-57.3 us, 44 VGPR, occ 41%) with two
// subtractive micro-cuts: (1) unclamped hrow[e] via 8-padded lists;
// (2) log2-domain softmax (exp2f; scores pre-scaled by log2e) — removes
// the hidden *1.4427 mul inside each __expf. No structural change: R10's
// packing and R10/R11's pipelining both regressed (gat is at a latency/
// issue balance point; occupancy loss beats chain savings).
__global__ void __launch_bounds__(256) gat_kernel(const float* __restrict__ z,
                                                  const unsigned short* __restrict__ hits_g,
                                                  const int* __restrict__ deg,
                                                  float* __restrict__ out) {
    const int tid = threadIdx.x, wv = tid >> 6, ln = tid & 63;
    const int blk = blockIdx.x;
    const int b = ((blk & 7) << 1) | (wv & 1);
    const int n = ((blk >> 3) << 1) | (wv >> 1);
    const int eq = ln >> 3, hq = ln & 7;

    const float* zb = z + ((size_t)b << 18);   // b*2048*128
    const int nh = min(deg[n], CAPR);
    const unsigned short* hrow = hits_g + n * CAPR;

    const float4* znp = (const float4*)(zb + ((size_t)n << 7) + (hq << 4));
    const float4 a0 = znp[0], a1 = znp[1], a2 = znp[2], a3 = znp[3];

    float m = NEG_INF, l = 0.f;   // m is in log2 domain (score * log2e)
    float4 acc0 = make_float4(0.f, 0.f, 0.f, 0.f), acc1 = acc0, acc2 = acc0, acc3 = acc0;

#pragma unroll 2
    for (int c0 = 0; c0 < nh; c0 += 8) {
        const int e = c0 + eq;
        const int he = hrow[e];                  // list 8-padded: no clamp
        const float4* zc = (const float4*)(zb + ((size_t)he << 7) + (hq << 4));
        const float4 v0 = zc[0], v1 = zc[1], v2 = zc[2], v3 = zc[3];
        float pt = a0.x * v0.x + a0.y * v0.y + a0.z * v0.z + a0.w * v0.w
                 + a1.x * v1.x + a1.y * v1.y + a1.z * v1.z + a1.w * v1.w
                 + a2.x * v2.x + a2.y * v2.y + a2.z * v2.z + a2.w * v2.w
                 + a3.x * v3.x + a3.y * v3.y + a3.z * v3.z + a3.w * v3.w;
        pt += __shfl_xor(pt, 1, 64);
        pt += __shfl_xor(pt, 2, 64);
        pt += __shfl_xor(pt, 4, 64);             // full 128-dim dot in all hq lanes
        float sv = pt > 0.f ? pt : LEAK * pt;    // leaky_relu(0.1)
        sv *= LOG2E;                             // to log2 domain
        if (pt == 0.f || e >= nh) sv = NEG_INF;  // masked_fill(att==0) / pad

        const float mnew = fmaxf(m, sv);
        const float alpha = exp2f(m - mnew);     // 1 while m==mnew==NEG_INF
        const float pr = exp2f(sv - mnew);
        l = l * alpha + pr;
        acc0.x = acc0.x * alpha + pr * v0.x; acc0.y = acc0.y * alpha + pr * v0.y;
        acc0.z = acc0.z * alpha + pr * v0.z; acc0.w = acc0.w * alpha + pr * v0.w;
        acc1.x = acc1.x * alpha + pr * v1.x; acc1.y = acc1.y * alpha + pr * v1.y;
        acc1.z = acc1.z * alpha + pr * v1.z; acc1.w = acc1.w * alpha + pr * v1.w;
        acc2.x = acc2.x * alpha + pr * v2.x; acc2.y = acc2.y * alpha + pr * v2.y;
        acc2.z = acc2.z * alpha + pr * v2.z; acc2.w = acc2.w * alpha + pr * v2.w;
        acc3.x = acc3.x * alpha + pr * v3.x; acc3.y = acc3.y * alpha + pr * v3.y;
        acc3.z = acc3.z * alpha + pr * v3.z; acc3.w = acc3.w * alpha + pr * v3.w;
        m = mnew;
    }

    // ---- cross-eq merge: global row max, rescale, sum ----
    float M = m;
#pragma unroll
    for (int off = 8; off <= 32; off <<= 1) M = fmaxf(M, __shfl_xor(M, off, 64));

    if (nh > 0 && M > 0.5f * NEG_INF) {
        const float al = exp2f(m - M);           // 0 for all-pad lanes
        l *= al;
        acc0.x *= al; acc0.y *= al; acc0.z *= al; acc0.w *= al;
        acc1.x *= al; acc1.y *= al; acc1.z *= al; acc1.w *= al;
        acc2.x *= al; acc2.y *= al; acc2.z *= al; acc2.w *= al;
        acc3.x *= al; acc3.y *= al; acc3.z *= al; acc3.w *= al;
#pragma unroll
        for (int off = 8; off <= 32; off <<= 1) {
            l += __shfl_xor(l, off, 64);
            acc0.x += __shfl_xor(acc0.x, off, 64); acc0.y += __shfl_xor(acc0.y, off, 64);
            acc0.z += __shfl_xor(acc0.z, off, 64); acc0.w += __shfl_xor(acc0.w, off, 64);
            acc1.x += __shfl_xor(acc1.x, off, 64); acc1.y += __shfl_xor(acc1.y, off, 64);
            acc1.z += __shfl_xor(acc1.z, off, 64); acc1.w += __shfl_xor(acc1.w, off, 64);
            acc2.x += __shfl_xor(acc2.x, off, 64); acc2.y += __shfl_xor(acc2.y, off, 64);
            acc2.z += __shfl_xor(acc2.z, off, 64); acc2.w += __shfl_xor(acc2.w, off, 64);
            acc3.x += __shfl_xor(acc3.x, off, 64); acc3.y += __shfl_xor(acc3.y, off, 64);
            acc3.z += __shfl_xor(acc3.z, off, 64); acc3.w += __shfl_xor(acc3.w, off, 64);
        }
        const float inv = 1.f / l;
        acc0.x *= inv; acc0.y *= inv; acc0.z *= inv; acc0.w *= inv;
        acc1.x *= inv; acc1.y *= inv; acc1.z *= inv; acc1.w *= inv;
        acc2.x *= inv; acc2.y *= inv; acc2.z *= inv; acc2.w *= inv;
        acc3.x *= inv; acc3.y *= inv; acc3.z *= inv; acc3.w *= inv;
    } else {
        // no valid edge: softmax over uniform -1e16 row -> mean of z[b]
        acc0 = make_float4(0.f, 0.f, 0.f, 0.f); acc1 = acc0; acc2 = acc0; acc3 = acc0;
        for (int mm = 0; mm < NN; ++mm) {
            const float4* zr = (const float4*)(zb + ((size_t)mm << 7) + (hq << 4));
            const float4 t0 = zr[0], t1 = zr[1], t2 = zr[2], t3 = zr[3];
            acc0.x += t0.x; acc0.y += t0.y; acc0.z += t0.z; acc0.w += t0.w;
            acc1.x += t1.x; acc1.y += t1.y; acc1.z += t1.z; acc1.w += t1.w;
            acc2.x += t2.x; acc2.y += t2.y; acc2.z += t2.z; acc2.w += t2.w;
            acc3.x += t3.x; acc3.y += t3.y; acc3.z += t3.z; acc3.w += t3.w;
        }
        const float s = 1.f / NN;
        acc0.x *= s; acc0.y *= s; acc0.z *= s; acc0.w *= s;
        acc1.x *= s; acc1.y *= s; acc1.z *= s; acc1.w *= s;
        acc2.x *= s; acc2.y *= s; acc2.z *= s; acc2.w *= s;
        acc3.x *= s; acc3.y *= s; acc3.z *= s; acc3.w *= s;
    }

    // store: lanes with eq<4 write float4 #eq of their hq slice (512 B/row)
    if (eq < 4) {
        float4 o = acc0;
        if (eq == 1) o = acc1;
        if (eq == 2) o = acc2;
        if (eq == 3) o = acc3;
        *(float4*)(out + (((size_t)b * NN + n) << 7) + (hq << 4) + (eq << 2)) = o;
    }
}

// ---------------- launcher ----------------
extern "C" void kernel_launch(void* const* d_in, const int* in_sizes, int n_in,
                              void* d_out, int out_size, void* d_ws, size_t ws_size,
                              hipStream_t stream) {
    const float* h = (const float*)d_in[0];
    const float* W = (const float*)d_in[1];
    const int* row = (const int*)d_in[2];
    const int* col = (const int*)d_in[3];
    float* out = (float*)d_out;

    char* ws = (char*)d_ws;
    float* z = (float*)ws;                                                     // 16 MB
    unsigned int* mask = (unsigned int*)(ws + (size_t)16 * 1024 * 1024);       // 512 KB
    unsigned short* hits_g = (unsigned short*)(ws + (size_t)16 * 1024 * 1024 + 512 * 1024); // 512 KB
    int* deg = (int*)(ws + (size_t)17 * 1024 * 1024);                          // 8 KB

    hipMemsetAsync(mask, 0, (size_t)NN * NN / 8, stream);   // DMA, ~2 us
    zedge_kernel<<<1280, 256, 0, stream>>>(h, W, z, row, col, mask);
    csr_kernel<<<NN / 4, 256, 0, stream>>>(mask, hits_g, deg);
    gat_kernel<<<(BC * NN) / 4, 256, 0, stream>>>(z, hits_g, deg, out);
}

// Round 13
// 151.121 us; speedup vs baseline: 1.0350x; 1.0104x over previous
//
#include <hip/hip_runtime.h>

#define BC 16
#define NN 2048
#define FF 128
#define DD 128
#define NEDGES 65536
#define NEG_INF -1e16f
#define LEAK 0.1f
#define CAPR 128   // per-row in-degree cap; P(Poisson(32) > 128) ~ 1e-35

// ---------------- Kernel 1 (fused): edge atomicOr + z = h @ W ------------
// blocks 0..255: set adjacency bits (mask pre-zeroed by hipMemsetAsync).
// blocks 256..1279: register-tiled zgemm, one [32 x 128] tile of z each.
__global__ void __launch_bounds__(256) zedge_kernel(const float* __restrict__ h,
                                                    const float* __restrict__ W,
                                                    float* __restrict__ z,
                                                    const int* __restrict__ row,
                                                    const int* __restrict__ col,
                                                    unsigned int* __restrict__ mask) {
    const int tid = threadIdx.x;
    const int blk = blockIdx.x;

    if (blk < 256) {   // ---- edge part
        const int e = blk * 256 + tid;
        const unsigned int key = (unsigned int)row[e] * NN + (unsigned int)col[e];
        atomicOr(&mask[key >> 5], 1u << (key & 31u));
        return;
    }

    // ---- zgemm part
    __shared__ float hs[32][FF];   // 16 KB
    const size_t row0 = (size_t)(blk - 256) * 32;
    const float4* hv = (const float4*)(h + row0 * FF);
    float4* hsv = (float4*)&hs[0][0];
#pragma unroll
    for (int i = 0; i < 4; ++i) hsv[tid + 256 * i] = hv[tid + 256 * i];
    __syncthreads();

    const int c0 = (tid & 31) * 4;
    const int r0 = (tid >> 5) * 4;
    float acc[4][4] = {};
    for (int f = 0; f < FF; f += 4) {
        float4 a[4], bb[4];
#pragma unroll
        for (int r = 0; r < 4; ++r) a[r] = *(const float4*)&hs[r0 + r][f];
#pragma unroll
        for (int k = 0; k < 4; ++k) bb[k] = *(const float4*)&W[(f + k) * DD + c0];
#pragma unroll
        for (int r = 0; r < 4; ++r) {
            acc[r][0] += a[r].x * bb[0].x + a[r].y * bb[1].x + a[r].z * bb[2].x + a[r].w * bb[3].x;
            acc[r][1] += a[r].x * bb[0].y + a[r].y * bb[1].y + a[r].z * bb[2].y + a[r].w * bb[3].y;
            acc[r][2] += a[r].x * bb[0].z + a[r].y * bb[1].z + a[r].z * bb[2].z + a[r].w * bb[3].z;
            acc[r][3] += a[r].x * bb[0].w + a[r].y * bb[1].w + a[r].z * bb[2].w + a[r].w * bb[3].w;
        }
    }
#pragma unroll
    for (int r = 0; r < 4; ++r)
        *(float4*)&z[(row0 + r0 + r) * DD + c0] =
            make_float4(acc[r][0], acc[r][1], acc[r][2], acc[r][3]);
}

// ---------------- Kernel 2: bitmask -> sorted CSR, zero atomics ----------
// one wave per row. Lane ln owns mask word ln (64 words = 2048 cols).
// Exclusive shuffle prefix-scan of popcounts gives each lane its slot base;
// bits decode in ascending column order -> gat gathers walk z[b] forward.
__global__ void __launch_bounds__(256) csr_kernel(const unsigned int* __restrict__ mask,
                                                  unsigned short* __restrict__ hits_g,
                                                  int* __restrict__ deg) {
    const int tid = threadIdx.x, wv = tid >> 6, ln = tid & 63;
    const int n = blockIdx.x * 4 + wv;
    unsigned int bits = mask[n * 64 + ln];
    const int cnt = __popc(bits);
    int pre = cnt;
#pragma unroll
    for (int off = 1; off <= 32; off <<= 1) {
        const int t = __shfl_up(pre, off, 64);
        if (ln >= off) pre += t;
    }
    if (ln == 63) deg[n] = pre;        // inclusive total (gat clamps at CAPR)
    int slot = pre - cnt;              // exclusive prefix = this lane's base
    while (bits) {
        const int bit = __ffs(bits) - 1;
        bits &= bits - 1;
        if (slot < CAPR) hits_g[n * CAPR + slot] = (unsigned short)(ln * 32 + bit);
        ++slot;
    }
}

// ---------------- Kernel 3: single-pass, lane-local online softmax -------
// CHAMPION (R9): 57.0-57.3 us, 44 VGPR, occ 41%, zero LDS/barriers/conflicts.
// One wave per (b,n) row, 4 independent waves/block.
// b = ((blk&7)<<1)|(wv&1): round-robin XCD mapping pins batches {2x,2x+1}
// (2 MB of z) in each XCD's 4 MB L2. Lane = (eq 0..7, hq 0..7).
// Each eq-group runs online softmax over its own edge subset with lane-local
// (m,l) — the only cross-lane ops in the loop are the 3 dot shuffles, which
// carry no loop dependence and pipeline ahead. One cross-eq merge at the end.
// Verified plateau: v4f packing (R10), score-stage pipelining (R11), and
// log2/unclamped micro-cuts (R12) all measured neutral or worse — gat sits
// at a VALU/L2-latency/occupancy balance point.
__global__ void __launch_bounds__(256) gat_kernel(const float* __restrict__ z,
                                                  const unsigned short* __restrict__ hits_g,
                                                  const int* __restrict__ deg,
                                                  float* __restrict__ out) {
    const int tid = threadIdx.x, wv = tid >> 6, ln = tid & 63;
    const int blk = blockIdx.x;
    const int b = ((blk & 7) << 1) | (wv & 1);
    const int n = ((blk >> 3) << 1) | (wv >> 1);
    const int eq = ln >> 3, hq = ln & 7;

    const float* zb = z + ((size_t)b << 18);   // b*2048*128
    const int nh = min(deg[n], CAPR);
    const unsigned short* hrow = hits_g + n * CAPR;

    const float4* znp = (const float4*)(zb + ((size_t)n << 7) + (hq << 4));
    const float4 a0 = znp[0], a1 = znp[1], a2 = znp[2], a3 = znp[3];

    float m = NEG_INF, l = 0.f;
    float4 acc0 = make_float4(0.f, 0.f, 0.f, 0.f), acc1 = acc0, acc2 = acc0, acc3 = acc0;

#pragma unroll 2
    for (int c0 = 0; c0 < nh; c0 += 8) {
        const int e = c0 + eq;
        const int he = hrow[min(e, nh - 1)];     // pad lanes re-read a real edge
        const float4* zc = (const float4*)(zb + ((size_t)he << 7) + (hq << 4));
        const float4 v0 = zc[0], v1 = zc[1], v2 = zc[2], v3 = zc[3];
        float pt = a0.x * v0.x + a0.y * v0.y + a0.z * v0.z + a0.w * v0.w
                 + a1.x * v1.x + a1.y * v1.y + a1.z * v1.z + a1.w * v1.w
                 + a2.x * v2.x + a2.y * v2.y + a2.z * v2.z + a2.w * v2.w
                 + a3.x * v3.x + a3.y * v3.y + a3.z * v3.z + a3.w * v3.w;
        pt += __shfl_xor(pt, 1, 64);
        pt += __shfl_xor(pt, 2, 64);
        pt += __shfl_xor(pt, 4, 64);             // full 128-dim dot in all hq lanes
        float sv = pt > 0.f ? pt : LEAK * pt;    // leaky_relu(0.1)
        if (sv == 0.f || e >= nh) sv = NEG_INF;  // masked_fill(att==0) / pad

        const float mnew = fmaxf(m, sv);
        const float alpha = __expf(m - mnew);    // 1 while m==mnew==NEG_INF
        const float pr = __expf(sv - mnew);
        l = l * alpha + pr;
        acc0.x = acc0.x * alpha + pr * v0.x; acc0.y = acc0.y * alpha + pr * v0.y;
        acc0.z = acc0.z * alpha + pr * v0.z; acc0.w = acc0.w * alpha + pr * v0.w;
        acc1.x = acc1.x * alpha + pr * v1.x; acc1.y = acc1.y * alpha + pr * v1.y;
        acc1.z = acc1.z * alpha + pr * v1.z; acc1.w = acc1.w * alpha + pr * v1.w;
        acc2.x = acc2.x * alpha + pr * v2.x; acc2.y = acc2.y * alpha + pr * v2.y;
        acc2.z = acc2.z * alpha + pr * v2.z; acc2.w = acc2.w * alpha + pr * v2.w;
        acc3.x = acc3.x * alpha + pr * v3.x; acc3.y = acc3.y * alpha + pr * v3.y;
        acc3.z = acc3.z * alpha + pr * v3.z; acc3.w = acc3.w * alpha + pr * v3.w;
        m = mnew;
    }

    float M = m;
#pragma unroll
    for (int off = 8; off <= 32; off <<= 1) M = fmaxf(M, __shfl_xor(M, off, 64));

    if (nh > 0 && M > 0.5f * NEG_INF) {
        const float al = __expf(m - M);          // 0 for all-pad lanes
        l *= al;
        acc0.x *= al; acc0.y *= al; acc0.z *= al; acc0.w *= al;
        acc1.x *= al; acc1.y *= al; acc1.z *= al; acc1.w *= al;
        acc2.x *= al; acc2.y *= al; acc2.z *= al; acc2.w *= al;
        acc3.x *= al; acc3.y *= al; acc3.z *= al; acc3.w *= al;
#pragma unroll
        for (int off = 8; off <= 32; off <<= 1) {
            l += __shfl_xor(l, off, 64);
            acc0.x += __shfl_xor(acc0.x, off, 64); acc0.y += __shfl_xor(acc0.y, off, 64);
            acc0.z += __shfl_xor(acc0.z, off, 64); acc0.w += __shfl_xor(acc0.w, off, 64);
            acc1.x += __shfl_xor(acc1.x, off, 64); acc1.y += __shfl_xor(acc1.y, off, 64);
            acc1.z += __shfl_xor(acc1.z, off, 64); acc1.w += __shfl_xor(acc1.w, off, 64);
            acc2.x += __shfl_xor(acc2.x, off, 64); acc2.y += __shfl_xor(acc2.y, off, 64);
            acc2.z += __shfl_xor(acc2.z, off, 64); acc2.w += __shfl_xor(acc2.w, off, 64);
            acc3.x += __shfl_xor(acc3.x, off, 64); acc3.y += __shfl_xor(acc3.y, off, 64);
            acc3.z += __shfl_xor(acc3.z, off, 64); acc3.w += __shfl_xor(acc3.w, off, 64);
        }
        const float inv = 1.f / l;
        acc0.x *= inv; acc0.y *= inv; acc0.z *= inv; acc0.w *= inv;
        acc1.x *= inv; acc1.y *= inv; acc1.z *= inv; acc1.w *= inv;
        acc2.x *= inv; acc2.y *= inv; acc2.z *= inv; acc2.w *= inv;
        acc3.x *= inv; acc3.y *= inv; acc3.z *= inv; acc3.w *= inv;
    } else {
        // no valid edge: softmax over uniform -1e16 row -> mean of z[b]
        acc0 = make_float4(0.f, 0.f, 0.f, 0.f); acc1 = acc0; acc2 = acc0; acc3 = acc0;
        for (int mm = 0; mm < NN; ++mm) {
            const float4* zr = (const float4*)(zb + ((size_t)mm << 7) + (hq << 4));
            const float4 t0 = zr[0], t1 = zr[1], t2 = zr[2], t3 = zr[3];
            acc0.x += t0.x; acc0.y += t0.y; acc0.z += t0.z; acc0.w += t0.w;
            acc1.x += t1.x; acc1.y += t1.y; acc1.z += t1.z; acc1.w += t1.w;
            acc2.x += t2.x; acc2.y += t2.y; acc2.z += t2.z; acc2.w += t2.w;
            acc3.x += t3.x; acc3.y += t3.y; acc3.z += t3.z; acc3.w += t3.w;
        }
        const float s = 1.f / NN;
        acc0.x *= s; acc0.y *= s; acc0.z *= s; acc0.w *= s;
        acc1.x *= s; acc1.y *= s; acc1.z *= s; acc1.w *= s;
        acc2.x *= s; acc2.y *= s; acc2.z *= s; acc2.w *= s;
        acc3.x *= s; acc3.y *= s; acc3.z *= s; acc3.w *= s;
    }

    if (eq < 4) {
        float4 o = acc0;
        if (eq == 1) o = acc1;
        if (eq == 2) o = acc2;
        if (eq == 3) o = acc3;
        *(float4*)(out + (((size_t)b * NN + n) << 7) + (hq << 4) + (eq << 2)) = o;
    }
}

// ---------------- launcher ----------------
extern "C" void kernel_launch(void* const* d_in, const int* in_sizes, int n_in,
                              void* d_out, int out_size, void* d_ws, size_t ws_size,
                              hipStream_t stream) {
    const float* h = (const float*)d_in[0];
    const float* W = (const float*)d_in[1];
    const int* row = (const int*)d_in[2];
    const int* col = (const int*)d_in[3];
    float* out = (float*)d_out;

    char* ws = (char*)d_ws;
    float* z = (float*)ws;                                                     // 16 MB
    unsigned int* mask = (unsigned int*)(ws + (size_t)16 * 1024 * 1024);       // 512 KB
    unsigned short* hits_g = (unsigned short*)(ws + (size_t)16 * 1024 * 1024 + 512 * 1024); // 512 KB
    int* deg = (int*)(ws + (size_t)17 * 1024 * 1024);                          // 8 KB

    hipMemsetAsync(mask, 0, (size_t)NN * NN / 8, stream);   // DMA, ~2 us
    zedge_kernel<<<1280, 256, 0, stream>>>(h, W, z, row, col, mask);
    csr_kernel<<<NN / 4, 256, 0, stream>>>(mask, hits_g, deg);
    gat_kernel<<<(BC * NN) / 4, 256, 0, stream>>>(z, hits_g, deg, out);
}